// Round 9
// baseline (515.883 us; speedup 1.0000x reference)
//
#include <hip/hip_runtime.h>
#include <math.h>

#define EMB   1024
#define S_LEN 1024
#define NQ    32
#define HEADS 16
#define FFN   4096
#define T_TOK 8192
#define EPS   1e-5f
#define MiB   (1024ull * 1024ull)

typedef unsigned short u16;
typedef __attribute__((ext_vector_type(8))) short short8;
typedef __attribute__((ext_vector_type(4))) float float4_t;

__device__ __forceinline__ u16 f2bf(float f) {
    unsigned u = __float_as_uint(f);
    u += 0x7FFF + ((u >> 16) & 1);   // round-to-nearest-even
    return (u16)(u >> 16);
}
__device__ __forceinline__ void async16(u16* lds, const u16* g) {
    __builtin_amdgcn_global_load_lds(
        (const __attribute__((address_space(1))) unsigned int*)g,
        (__attribute__((address_space(3))) unsigned int*)lds, 16, 0, 0);
}

// ---- K0: w1,w2 f32 -> bf16 for MFMA ---------------------------------------
__global__ __launch_bounds__(256) void k_conv_w(
        const float* __restrict__ w1, const float* __restrict__ w2,
        u16* __restrict__ w1b, u16* __restrict__ w2b) {
    int idx = blockIdx.x * 256 + threadIdx.x;
    if (idx < FFN * NQ) w1b[idx] = f2bf(w1[idx]);
    else                w2b[idx - FFN * NQ] = f2bf(w2[idx - FFN * NQ]);
}

// ---- K1: qv[(b*16+h)*S+s][c] = cos(tha[i])cos(x[t][i]), i=2h+c ------------
__global__ __launch_bounds__(256) void k_qv(const float* __restrict__ x,
                                            const float* __restrict__ tha,
                                            float* __restrict__ qv) {
    int idx = blockIdx.x * 256 + threadIdx.x;
    int i = idx & 31;
    int t = idx >> 5;
    int b = t >> 10, s = t & 1023;
    float cv = __cosf(tha[i]) * __cosf(x[(size_t)t * EMB + i]);
    int h = i >> 1, c = i & 1;
    qv[(((size_t)(b * HEADS + h)) * S_LEN + s) * 2 + c] = cv;
}

// ---- K2: per-(b,h) softmax attention, dk=2 (no max-sub: |score|<=sqrt2) ---
__global__ __launch_bounds__(256) void k_attn(const float* __restrict__ qv,
                                              float* __restrict__ attn) {
    __shared__ __align__(16) float2 kv[S_LEN];
    int bh  = blockIdx.x;
    int tid = threadIdx.x;
    const float2* base = (const float2*)(qv + (size_t)bh * S_LEN * 2);
    for (int i = tid; i < S_LEN; i += 256) kv[i] = base[i];
    __syncthreads();
    int s = blockIdx.y * 256 + tid;
    float2 q = kv[s];
    float qx = q.x * 0.70710678f, qy = q.y * 0.70710678f;
    float den = 0.f, nx = 0.f, ny = 0.f;
#pragma unroll 4
    for (int t = 0; t < S_LEN; ++t) {
        float2 k = kv[t];
        float d = fmaf(qy, k.y, qx * k.x);
        float e = __expf(d);
        den += e;
        nx = fmaf(e, k.x, nx);
        ny = fmaf(e, k.y, ny);
    }
    float inv = 1.f / den;
    float* o = attn + ((size_t)bh * S_LEN + s) * 2;
    o[0] = nx * inv;
    o[1] = ny * inv;
}

// ---- K3: y = x + attn@wc^T ; LN1 -> x1 f32 ; qf bf16 ----------------------
__global__ __launch_bounds__(256) void k_combine_ln1(
        const float* __restrict__ x, const float* __restrict__ attn,
        const float* __restrict__ wc, const float* __restrict__ g1,
        const float* __restrict__ b1, const float* __restrict__ thf,
        float* __restrict__ x1, u16* __restrict__ qf) {
    __shared__ float sa[NQ];
    __shared__ float red[8];
    int t = blockIdx.x;
    int b = t >> 10, s = t & 1023;
    int tid = threadIdx.x, lane = tid & 63, wave = tid >> 6;
    if (tid < NQ) {
        int h = tid >> 1, c = tid & 1;
        sa[tid] = attn[(((size_t)(b * HEADS + h)) * S_LEN + s) * 2 + c];
    }
    __syncthreads();
    int e0 = tid * 4;
    float4 xv = *(const float4*)(x + (size_t)t * EMB + e0);
    float y[4] = {xv.x, xv.y, xv.z, xv.w};
#pragma unroll
    for (int j = 0; j < 4; ++j) {
        const float* wr = wc + (size_t)(e0 + j) * NQ;
        float a = 0.f;
#pragma unroll
        for (int i = 0; i < NQ; ++i) a = fmaf(sa[i], wr[i], a);
        y[j] += a;
    }
    float sm = y[0] + y[1] + y[2] + y[3];
    float sq = y[0]*y[0] + y[1]*y[1] + y[2]*y[2] + y[3]*y[3];
    for (int o = 32; o > 0; o >>= 1) {
        sm += __shfl_xor(sm, o, 64);
        sq += __shfl_xor(sq, o, 64);
    }
    if (lane == 0) { red[wave * 2] = sm; red[wave * 2 + 1] = sq; }
    __syncthreads();
    sm = red[0] + red[2] + red[4] + red[6];
    sq = red[1] + red[3] + red[5] + red[7];
    float mu  = sm * (1.f / EMB);
    float var = sq * (1.f / EMB) - mu * mu;
    float rs  = rsqrtf(var + EPS);
    float4 o4;
    float* ov = (float*)&o4;
#pragma unroll
    for (int j = 0; j < 4; ++j) {
        int e = e0 + j;
        float v = (y[j] - mu) * rs * g1[e] + b1[e];
        ov[j] = v;
        if (e < NQ)
            qf[(size_t)t * NQ + e] = f2bf(__cosf(thf[e]) * __cosf(v));
    }
    *(float4*)(x1 + (size_t)t * EMB + e0) = o4;
}

// ---- K4: fused FFN: Y(f32) = x1(f32) + relu(qf@w1^T)@w2^T -----------------
// 128x128 tile; per 64-wide k-step: h-tile via MFMA from register qf frag +
// LDS w1 slice (relu->bf16->LDS), then m97-style MFMA vs staged w2 tile.
__global__ __launch_bounds__(256) void k_ffn_fused(
        const u16* __restrict__ QF,     // [T,32]  bf16
        const u16* __restrict__ W1,     // [FFN,32] bf16
        const u16* __restrict__ W2,     // [EMB,FFN] bf16
        const float* __restrict__ X1,   // [T,EMB] f32 residual
        float* __restrict__ Y) {        // [T,EMB] f32 pre-LN out (d_out)
    const int K = FFN, N = EMB;
    __shared__ __align__(16) u16 sW[64 * 32];
    __shared__ __align__(16) u16 sA[128 * 64];
    __shared__ __align__(16) u16 sB[128 * 64];
    int tid = threadIdx.x, lane = tid & 63, wave = tid >> 6;
    int m0 = blockIdx.y * 128, n0 = blockIdx.x * 128;
    int wm = (wave >> 1) * 64, wn = (wave & 1) * 64;

    short8 aq[2];
#pragma unroll
    for (int tm2 = 0; tm2 < 2; ++tm2) {
        int m = m0 + wave * 32 + tm2 * 16 + (lane & 15);
        aq[tm2] = *(const short8*)(QF + (size_t)m * 32 + (lane >> 4) * 8);
    }
    const u16* gB = W2 + (size_t)(n0 + wave * 32 + (lane >> 3)) * K + (lane & 7) * 8;
    const u16* gW = W1 + (size_t)(wave * 16 + (lane >> 2)) * 32 + (lane & 3) * 8;

    float4_t acc[4][4];
    float4_t zero = {0.f, 0.f, 0.f, 0.f};
#pragma unroll
    for (int tm = 0; tm < 4; ++tm)
#pragma unroll
        for (int tn = 0; tn < 4; ++tn) acc[tm][tn] = zero;

    for (int kt = 0; kt < K; kt += 64) {
        async16(&sW[(size_t)(wave * 16) * 32], gW + (size_t)kt * 32);
#pragma unroll
        for (int i = 0; i < 4; ++i)
            async16(&sB[(size_t)(wave * 32 + i * 8) * 64], gB + (size_t)i * 8 * K + kt);
        __syncthreads();

        int r0 = (lane >> 4) * 4;
#pragma unroll
        for (int tm2 = 0; tm2 < 2; ++tm2) {
            int mrow = wave * 32 + tm2 * 16;
#pragma unroll
            for (int tf = 0; tf < 4; ++tf) {
                short8 bw = *(const short8*)&sW[(size_t)(tf * 16 + (lane & 15)) * 32 + (lane >> 4) * 8];
                float4_t d = __builtin_amdgcn_mfma_f32_16x16x32_bf16(aq[tm2], bw, zero, 0, 0, 0);
                int cc = tf * 16 + (lane & 15);
#pragma unroll
                for (int r = 0; r < 4; ++r)
                    sA[(size_t)(mrow + r0 + r) * 64 + cc] = f2bf(fmaxf(d[r], 0.f));
            }
        }
        __syncthreads();

#pragma unroll
        for (int kk = 0; kk < 2; ++kk) {
            short8 af[4], bfr[4];
#pragma unroll
            for (int tm = 0; tm < 4; ++tm)
                af[tm] = *(const short8*)&sA[(size_t)(wm + tm * 16 + (lane & 15)) * 64 + kk * 32 + (lane >> 4) * 8];
#pragma unroll
            for (int tn = 0; tn < 4; ++tn)
                bfr[tn] = *(const short8*)&sB[(size_t)(wn + tn * 16 + (lane & 15)) * 64 + kk * 32 + (lane >> 4) * 8];
#pragma unroll
            for (int tm = 0; tm < 4; ++tm)
#pragma unroll
                for (int tn = 0; tn < 4; ++tn)
                    acc[tm][tn] = __builtin_amdgcn_mfma_f32_16x16x32_bf16(af[tm], bfr[tn], acc[tm][tn], 0, 0, 0);
        }
        __syncthreads();
    }
    // epilogue: f32 residual add, f32 store
#pragma unroll
    for (int tm = 0; tm < 4; ++tm) {
        int mr = m0 + wm + tm * 16 + (lane >> 4) * 4;
#pragma unroll
        for (int tn = 0; tn < 4; ++tn) {
            int nc = n0 + wn + tn * 16 + (lane & 15);
#pragma unroll
            for (int r = 0; r < 4; ++r) {
                size_t off = (size_t)(mr + r) * N + nc;
                Y[off] = acc[tm][tn][r] + X1[off];
            }
        }
    }
}

// ---- K5: in-place LN2 on f32 d_out ----------------------------------------
__global__ __launch_bounds__(256) void k_ln2(float* __restrict__ y,
                                             const float* __restrict__ g2,
                                             const float* __restrict__ b2) {
    __shared__ float red[8];
    int t = blockIdx.x;
    int tid = threadIdx.x, lane = tid & 63, wave = tid >> 6;
    int e0 = tid * 4;
    float* row = y + (size_t)t * EMB;
    float4 v4 = *(const float4*)(row + e0);
    float v[4] = {v4.x, v4.y, v4.z, v4.w};
    float sm = v[0] + v[1] + v[2] + v[3];
    float sq = v[0]*v[0] + v[1]*v[1] + v[2]*v[2] + v[3]*v[3];
    for (int o = 32; o > 0; o >>= 1) {
        sm += __shfl_xor(sm, o, 64);
        sq += __shfl_xor(sq, o, 64);
    }
    if (lane == 0) { red[wave * 2] = sm; red[wave * 2 + 1] = sq; }
    __syncthreads();
    sm = red[0] + red[2] + red[4] + red[6];
    sq = red[1] + red[3] + red[5] + red[7];
    float mu  = sm * (1.f / EMB);
    float var = sq * (1.f / EMB) - mu * mu;
    float rs  = rsqrtf(var + EPS);
    float4 o4;
    o4.x = (v[0] - mu) * rs * g2[e0 + 0] + b2[e0 + 0];
    o4.y = (v[1] - mu) * rs * g2[e0 + 1] + b2[e0 + 1];
    o4.z = (v[2] - mu) * rs * g2[e0 + 2] + b2[e0 + 2];
    o4.w = (v[3] - mu) * rs * g2[e0 + 3] + b2[e0 + 3];
    *(float4*)(row + e0) = o4;
}

extern "C" void kernel_launch(void* const* d_in, const int* in_sizes, int n_in,
                              void* d_out, int out_size, void* d_ws, size_t ws_size,
                              hipStream_t stream) {
    const float* x   = (const float*)d_in[0];
    const float* tha = (const float*)d_in[1];
    const float* thf = (const float*)d_in[2];
    const float* wc  = (const float*)d_in[3];
    const float* w1  = (const float*)d_in[4];
    const float* w2  = (const float*)d_in[5];
    const float* g1  = (const float*)d_in[6];
    const float* b1  = (const float*)d_in[7];
    const float* g2  = (const float*)d_in[8];
    const float* b2  = (const float*)d_in[9];
    float* out = (float*)d_out;     // OUTPUT IS FLOAT32 (reference dtype)

    char* ws = (char*)d_ws;
    float* x1   = (float*)(ws);                 //  0 .. 32 MiB
    float* qv   = (float*)(ws + 32 * MiB);      // 32 .. 33 MiB
    float* attn = (float*)(ws + 33 * MiB);      // 33 .. 34 MiB
    u16*   qf   = (u16*)  (ws + 34 * MiB);      // 34 .. 34.5 MiB
    u16*   w1b  = (u16*)  (ws + 35 * MiB);      // 0.25 MiB
    u16*   w2b  = (u16*)  (ws + 36 * MiB);      // 36 .. 44 MiB

    k_conv_w<<<(FFN * NQ + EMB * FFN) / 256, 256, 0, stream>>>(w1, w2, w1b, w2b);
    k_qv<<<T_TOK * NQ / 256, 256, 0, stream>>>(x, tha, qv);
    k_attn<<<dim3(128, 4), 256, 0, stream>>>(qv, attn);
    k_combine_ln1<<<T_TOK, 256, 0, stream>>>(x, attn, wc, g1, b1, thf, x1, qf);
    k_ffn_fused<<<dim3(EMB / 128, T_TOK / 128), 256, 0, stream>>>(qf, w1b, w2b, x1, out);
    k_ln2<<<T_TOK, 256, 0, stream>>>(out, g2, b2);
}

// Round 10
// 376.315 us; speedup vs baseline: 1.3709x; 1.3709x over previous
//
#include <hip/hip_runtime.h>
#include <math.h>

#define EMB   1024
#define S_LEN 1024
#define NQ    32
#define HEADS 16
#define FFN   4096
#define T_TOK 8192
#define EPS   1e-5f
#define MiB   (1024ull * 1024ull)

typedef unsigned short u16;
typedef __attribute__((ext_vector_type(8))) short short8;
typedef __attribute__((ext_vector_type(4))) float float4_t;

__device__ __forceinline__ u16 f2bf(float f) {
    unsigned u = __float_as_uint(f);
    u += 0x7FFF + ((u >> 16) & 1);   // round-to-nearest-even
    return (u16)(u >> 16);
}
__device__ __forceinline__ void async16(u16* lds, const u16* g) {
    __builtin_amdgcn_global_load_lds(
        (const __attribute__((address_space(1))) unsigned int*)g,
        (__attribute__((address_space(3))) unsigned int*)lds, 16, 0, 0);
}

// ---- K0: w1,w2,wc f32 -> bf16 for MFMA ------------------------------------
#define N_W1 (FFN * NQ)            // 131072
#define N_W2 (EMB * FFN)           // 4194304
#define N_WC (EMB * NQ)            // 32768
__global__ __launch_bounds__(256) void k_conv(
        const float* __restrict__ w1, const float* __restrict__ w2,
        const float* __restrict__ wc, u16* __restrict__ w1b,
        u16* __restrict__ w2b, u16* __restrict__ wcb) {
    int idx = blockIdx.x * 256 + threadIdx.x;
    if (idx < N_W1)               w1b[idx] = f2bf(w1[idx]);
    else if (idx < N_W1 + N_W2)   w2b[idx - N_W1] = f2bf(w2[idx - N_W1]);
    else if (idx < N_W1 + N_W2 + N_WC) wcb[idx - N_W1 - N_W2] = f2bf(wc[idx - N_W1 - N_W2]);
}

// ---- K1: qv[(b*16+h)*S+s][c] = cos(tha[i])cos(x[t][i]), i=2h+c ------------
__global__ __launch_bounds__(256) void k_qv(const float* __restrict__ x,
                                            const float* __restrict__ tha,
                                            float* __restrict__ qv) {
    int idx = blockIdx.x * 256 + threadIdx.x;
    int i = idx & 31;
    int t = idx >> 5;
    int b = t >> 10, s = t & 1023;
    float cv = __cosf(tha[i]) * __cosf(x[(size_t)t * EMB + i]);
    int h = i >> 1, c = i & 1;
    qv[(((size_t)(b * HEADS + h)) * S_LEN + s) * 2 + c] = cv;
}

// ---- K2: per-(b,h) softmax attention, dk=2; bf16 token-major out ----------
__global__ __launch_bounds__(256) void k_attn(const float* __restrict__ qv,
                                              u16* __restrict__ attnB) {
    __shared__ __align__(16) float2 kv[S_LEN];
    int bh  = blockIdx.x;
    int tid = threadIdx.x;
    const float2* base = (const float2*)(qv + (size_t)bh * S_LEN * 2);
    for (int i = tid; i < S_LEN; i += 256) kv[i] = base[i];
    __syncthreads();
    int s = blockIdx.y * 256 + tid;
    float2 q = kv[s];
    float qx = q.x * 0.70710678f, qy = q.y * 0.70710678f;
    float den = 0.f, nx = 0.f, ny = 0.f;
#pragma unroll 4
    for (int t = 0; t < S_LEN; ++t) {
        float2 k = kv[t];
        float d = fmaf(qy, k.y, qx * k.x);
        float e = __expf(d);              // |d| <= sqrt(2): no max-sub
        den += e;
        nx = fmaf(e, k.x, nx);
        ny = fmaf(e, k.y, ny);
    }
    float inv = 1.f / den;
    int b = bh >> 4, h = bh & 15;
    u16* o = attnB + (size_t)(b * S_LEN + s) * NQ + 2 * h;
    o[0] = f2bf(nx * inv);
    o[1] = f2bf(ny * inv);
}

// ---- K3a: x1 = x + attn @ wc^T  (MFMA GEMM, M=8192 N=1024 K=32) -----------
__global__ __launch_bounds__(256) void k_combine_mfma(
        const u16* __restrict__ A,     // attnB [T,32] bf16
        const u16* __restrict__ B,     // wcb [EMB,32] bf16
        const float* __restrict__ X,   // x [T,EMB] f32
        float* __restrict__ Y) {       // x1 pre-LN [T,EMB] f32
    __shared__ __align__(16) u16 sA[128 * 32];
    __shared__ __align__(16) u16 sB[128 * 32];
    int tid = threadIdx.x, lane = tid & 63, wave = tid >> 6;
    int m0 = blockIdx.y * 128, n0 = blockIdx.x * 128;
    int wm = (wave >> 1) * 64, wn = (wave & 1) * 64;
    int srow = lane >> 2, scol = (lane & 3) * 8;   // 4 lanes per 64-B row
#pragma unroll
    for (int i = 0; i < 2; ++i) {
        int rb = wave * 32 + i * 16;               // 16 rows per async16
        async16(&sA[(size_t)rb * 32], A + (size_t)(m0 + rb + srow) * 32 + scol);
        async16(&sB[(size_t)rb * 32], B + (size_t)(n0 + rb + srow) * 32 + scol);
    }
    __syncthreads();
    short8 af[4], bfr[4];
#pragma unroll
    for (int tm = 0; tm < 4; ++tm)
        af[tm] = *(const short8*)&sA[(size_t)(wm + tm * 16 + (lane & 15)) * 32 + (lane >> 4) * 8];
#pragma unroll
    for (int tn = 0; tn < 4; ++tn)
        bfr[tn] = *(const short8*)&sB[(size_t)(wn + tn * 16 + (lane & 15)) * 32 + (lane >> 4) * 8];
    float4_t zero = {0.f, 0.f, 0.f, 0.f};
#pragma unroll
    for (int tm = 0; tm < 4; ++tm) {
        int mr = m0 + wm + tm * 16 + (lane >> 4) * 4;
#pragma unroll
        for (int tn = 0; tn < 4; ++tn) {
            float4_t acc = __builtin_amdgcn_mfma_f32_16x16x32_bf16(af[tm], bfr[tn], zero, 0, 0, 0);
            int nc = n0 + wn + tn * 16 + (lane & 15);
#pragma unroll
            for (int r = 0; r < 4; ++r) {
                size_t off = (size_t)(mr + r) * EMB + nc;
                Y[off] = acc[r] + X[off];
            }
        }
    }
}

// ---- K3b: LN1 in place on x1 ; qf bf16 ------------------------------------
__global__ __launch_bounds__(256) void k_ln1(float* __restrict__ x1,
                                             const float* __restrict__ g1,
                                             const float* __restrict__ b1,
                                             const float* __restrict__ thf,
                                             u16* __restrict__ qf) {
    __shared__ float red[8];
    int t = blockIdx.x;
    int tid = threadIdx.x, lane = tid & 63, wave = tid >> 6;
    int e0 = tid * 4;
    float* row = x1 + (size_t)t * EMB;
    float4 v4 = *(const float4*)(row + e0);
    float v[4] = {v4.x, v4.y, v4.z, v4.w};
    float sm = v[0] + v[1] + v[2] + v[3];
    float sq = v[0]*v[0] + v[1]*v[1] + v[2]*v[2] + v[3]*v[3];
    for (int o = 32; o > 0; o >>= 1) {
        sm += __shfl_xor(sm, o, 64);
        sq += __shfl_xor(sq, o, 64);
    }
    if (lane == 0) { red[wave * 2] = sm; red[wave * 2 + 1] = sq; }
    __syncthreads();
    sm = red[0] + red[2] + red[4] + red[6];
    sq = red[1] + red[3] + red[5] + red[7];
    float mu  = sm * (1.f / EMB);
    float var = sq * (1.f / EMB) - mu * mu;
    float rs  = rsqrtf(var + EPS);
    float4 o4;
    float* ov = (float*)&o4;
#pragma unroll
    for (int j = 0; j < 4; ++j) {
        int e = e0 + j;
        float y = (v[j] - mu) * rs * g1[e] + b1[e];
        ov[j] = y;
        if (e < NQ)
            qf[(size_t)t * NQ + e] = f2bf(__cosf(thf[e]) * __cosf(y));
    }
    *(float4*)(row + e0) = o4;
}

// ---- K4: fused FFN: Y(f32) = x1(f32) + relu(qf@w1^T)@w2^T -----------------
__global__ __launch_bounds__(256) void k_ffn_fused(
        const u16* __restrict__ QF,     // [T,32]  bf16
        const u16* __restrict__ W1,     // [FFN,32] bf16
        const u16* __restrict__ W2,     // [EMB,FFN] bf16
        const float* __restrict__ X1,   // [T,EMB] f32 residual
        float* __restrict__ Y) {        // [T,EMB] f32 pre-LN out (d_out)
    const int K = FFN, N = EMB;
    __shared__ __align__(16) u16 sW[64 * 32];
    __shared__ __align__(16) u16 sA[128 * 64];
    __shared__ __align__(16) u16 sB[128 * 64];
    int tid = threadIdx.x, lane = tid & 63, wave = tid >> 6;
    int m0 = blockIdx.y * 128, n0 = blockIdx.x * 128;
    int wm = (wave >> 1) * 64, wn = (wave & 1) * 64;

    short8 aq[2];
#pragma unroll
    for (int tm2 = 0; tm2 < 2; ++tm2) {
        int m = m0 + wave * 32 + tm2 * 16 + (lane & 15);
        aq[tm2] = *(const short8*)(QF + (size_t)m * 32 + (lane >> 4) * 8);
    }
    const u16* gB = W2 + (size_t)(n0 + wave * 32 + (lane >> 3)) * K + (lane & 7) * 8;
    const u16* gW = W1 + (size_t)(wave * 16 + (lane >> 2)) * 32 + (lane & 3) * 8;

    float4_t acc[4][4];
    float4_t zero = {0.f, 0.f, 0.f, 0.f};
#pragma unroll
    for (int tm = 0; tm < 4; ++tm)
#pragma unroll
        for (int tn = 0; tn < 4; ++tn) acc[tm][tn] = zero;

    for (int kt = 0; kt < K; kt += 64) {
        async16(&sW[(size_t)(wave * 16) * 32], gW + (size_t)kt * 32);
#pragma unroll
        for (int i = 0; i < 4; ++i)
            async16(&sB[(size_t)(wave * 32 + i * 8) * 64], gB + (size_t)i * 8 * K + kt);
        __syncthreads();

        int r0 = (lane >> 4) * 4;
#pragma unroll
        for (int tm2 = 0; tm2 < 2; ++tm2) {
            int mrow = wave * 32 + tm2 * 16;
#pragma unroll
            for (int tf = 0; tf < 4; ++tf) {
                short8 bw = *(const short8*)&sW[(size_t)(tf * 16 + (lane & 15)) * 32 + (lane >> 4) * 8];
                float4_t d = __builtin_amdgcn_mfma_f32_16x16x32_bf16(aq[tm2], bw, zero, 0, 0, 0);
                int cc = tf * 16 + (lane & 15);
#pragma unroll
                for (int r = 0; r < 4; ++r)
                    sA[(size_t)(mrow + r0 + r) * 64 + cc] = f2bf(fmaxf(d[r], 0.f));
            }
        }
        __syncthreads();

#pragma unroll
        for (int kk = 0; kk < 2; ++kk) {
            short8 af[4], bfr[4];
#pragma unroll
            for (int tm = 0; tm < 4; ++tm)
                af[tm] = *(const short8*)&sA[(size_t)(wm + tm * 16 + (lane & 15)) * 64 + kk * 32 + (lane >> 4) * 8];
#pragma unroll
            for (int tn = 0; tn < 4; ++tn)
                bfr[tn] = *(const short8*)&sB[(size_t)(wn + tn * 16 + (lane & 15)) * 64 + kk * 32 + (lane >> 4) * 8];
#pragma unroll
            for (int tm = 0; tm < 4; ++tm)
#pragma unroll
                for (int tn = 0; tn < 4; ++tn)
                    acc[tm][tn] = __builtin_amdgcn_mfma_f32_16x16x32_bf16(af[tm], bfr[tn], acc[tm][tn], 0, 0, 0);
        }
        __syncthreads();
    }
#pragma unroll
    for (int tm = 0; tm < 4; ++tm) {
        int mr = m0 + wm + tm * 16 + (lane >> 4) * 4;
#pragma unroll
        for (int tn = 0; tn < 4; ++tn) {
            int nc = n0 + wn + tn * 16 + (lane & 15);
#pragma unroll
            for (int r = 0; r < 4; ++r) {
                size_t off = (size_t)(mr + r) * N + nc;
                Y[off] = acc[tm][tn][r] + X1[off];
            }
        }
    }
}

// ---- K5: in-place LN2 on f32 d_out ----------------------------------------
__global__ __launch_bounds__(256) void k_ln2(float* __restrict__ y,
                                             const float* __restrict__ g2,
                                             const float* __restrict__ b2) {
    __shared__ float red[8];
    int t = blockIdx.x;
    int tid = threadIdx.x, lane = tid & 63, wave = tid >> 6;
    int e0 = tid * 4;
    float* row = y + (size_t)t * EMB;
    float4 v4 = *(const float4*)(row + e0);
    float v[4] = {v4.x, v4.y, v4.z, v4.w};
    float sm = v[0] + v[1] + v[2] + v[3];
    float sq = v[0]*v[0] + v[1]*v[1] + v[2]*v[2] + v[3]*v[3];
    for (int o = 32; o > 0; o >>= 1) {
        sm += __shfl_xor(sm, o, 64);
        sq += __shfl_xor(sq, o, 64);
    }
    if (lane == 0) { red[wave * 2] = sm; red[wave * 2 + 1] = sq; }
    __syncthreads();
    sm = red[0] + red[2] + red[4] + red[6];
    sq = red[1] + red[3] + red[5] + red[7];
    float mu  = sm * (1.f / EMB);
    float var = sq * (1.f / EMB) - mu * mu;
    float rs  = rsqrtf(var + EPS);
    float4 o4;
    o4.x = (v[0] - mu) * rs * g2[e0 + 0] + b2[e0 + 0];
    o4.y = (v[1] - mu) * rs * g2[e0 + 1] + b2[e0 + 1];
    o4.z = (v[2] - mu) * rs * g2[e0 + 2] + b2[e0 + 2];
    o4.w = (v[3] - mu) * rs * g2[e0 + 3] + b2[e0 + 3];
    *(float4*)(row + e0) = o4;
}

extern "C" void kernel_launch(void* const* d_in, const int* in_sizes, int n_in,
                              void* d_out, int out_size, void* d_ws, size_t ws_size,
                              hipStream_t stream) {
    const float* x   = (const float*)d_in[0];
    const float* tha = (const float*)d_in[1];
    const float* thf = (const float*)d_in[2];
    const float* wc  = (const float*)d_in[3];
    const float* w1  = (const float*)d_in[4];
    const float* w2  = (const float*)d_in[5];
    const float* g1  = (const float*)d_in[6];
    const float* b1  = (const float*)d_in[7];
    const float* g2  = (const float*)d_in[8];
    const float* b2  = (const float*)d_in[9];
    float* out = (float*)d_out;     // f32 output (reference dtype)

    char* ws = (char*)d_ws;
    float* x1    = (float*)(ws);                 //  0 .. 32 MiB
    float* qv    = (float*)(ws + 32 * MiB);      // 32 .. 33 MiB
    u16*   attnB = (u16*)  (ws + 33 * MiB);      // 0.5 MiB
    u16*   qf    = (u16*)  (ws + 34 * MiB);      // 0.5 MiB
    u16*   w1b   = (u16*)  (ws + 35 * MiB);      // 0.25 MiB
    u16*   w2b   = (u16*)  (ws + 36 * MiB);      // 36 .. 44 MiB
    u16*   wcb   = (u16*)  (ws + 44 * MiB);      // 64 KiB

    k_conv<<<(N_W1 + N_W2 + N_WC + 255) / 256, 256, 0, stream>>>(
        w1, w2, wc, w1b, w2b, wcb);
    k_qv<<<T_TOK * NQ / 256, 256, 0, stream>>>(x, tha, qv);
    k_attn<<<dim3(128, 4), 256, 0, stream>>>(qv, attnB);
    k_combine_mfma<<<dim3(EMB / 128, T_TOK / 128), 256, 0, stream>>>(
        attnB, wcb, x, x1);
    k_ln1<<<T_TOK, 256, 0, stream>>>(x1, g1, b1, thf, qf);
    k_ffn_fused<<<dim3(EMB / 128, T_TOK / 128), 256, 0, stream>>>(
        qf, w1b, w2b, x1, out);
    k_ln2<<<T_TOK, 256, 0, stream>>>(out, g2, b2);
}